// Round 6
// baseline (110.141 us; speedup 1.0000x reference)
//
#include <hip/hip_runtime.h>

// Problem constants (GATLayer): B=4, N=2048, TOKEN_DIM=512, HIDDEN=128
// IO dtype: fp32. Internally: bf16 MFMA with fp32 accumulate.
// v12: three dispatches.
//   k_prep : fc_w fp32 -> bf16 (RTNE) once into workspace.   [unchanged]
//   k_fused: v9 shape (256 blocks x 1024 thr).               [unchanged]
//   k_attn : WAVE-SPECIALIZED producer/consumer. Waves 0-3 produce exp(P)
//            tiles (pure VALU); waves 4-7 consume (B-loads + ds_read + MFMA).
//            Each SIMD hosts 1 producer + 1 consumer wave -> VALU and MFMA/
//            memory pipes overlap (m114 co-scheduling) instead of the old
//            barrier-locked phase alternation. Consumer A-reads feed 4 MFMAs
//            (2 i-subtiles x 2 d-tiles) -> LDS reads halve vs v9. Barriers
//            only at uniform program points (no divergent barriers).
#define NB      4
#define NTOK    2048
#define TOKDIM  512
#define HID     128
#define NROWS   (NB * NTOK)      // 8192
#define LN_EPS  1e-5f
#define NEG_SLOPE 0.01f

typedef short bf16x8 __attribute__((ext_vector_type(8)));   // 8 bf16 in 4 VGPRs
typedef float f32x4  __attribute__((ext_vector_type(4)));

static __device__ __forceinline__ unsigned short f2bf(float f) {
    union { float f; unsigned int i; } v; v.f = f;
    unsigned int i = v.i;
    i += 0x7FFFu + ((i >> 16) & 1u);   // round-to-nearest-even
    return (unsigned short)(i >> 16);
}

// ---------------------------------------------------------------------------
// k_prep: convert fc_w (128x512 fp32) -> bf16 once. 64 blocks x 256 thr.
// ---------------------------------------------------------------------------
__global__ __launch_bounds__(256) void k_prep(const float* __restrict__ W,
                                              unsigned short* __restrict__ Wb) {
    const int g = blockIdx.x * 256 + threadIdx.x;   // 0..16383
    float4 v = *(const float4*)(W + (size_t)g * 4);
    ushort4 o;
    o.x = f2bf(v.x); o.y = f2bf(v.y); o.z = f2bf(v.z); o.w = f2bf(v.w);
    *(ushort4*)(Wb + (size_t)g * 4) = o;
}

// ---------------------------------------------------------------------------
// k_fused (v9, unchanged): per 32-row tile: FC (MFMA) + bias + LN + scores
// + transposed hT. Grid 256 blocks x 1024 thr (16 waves). Wave wv: n-cols
// [(wv&7)*16,+16), row-half (wv>>3)*16. Twin waves share Wb slices via L1.
// ---------------------------------------------------------------------------
__global__ __launch_bounds__(1024) void k_fused(const float* __restrict__ X,
                                                const unsigned short* __restrict__ Wb,
                                                const float* __restrict__ fcb,
                                                const float* __restrict__ attnw,
                                                const float* __restrict__ attnb,
                                                const float* __restrict__ lng,
                                                const float* __restrict__ lnb,
                                                unsigned short* __restrict__ hT,
                                                float* __restrict__ srow,
                                                float* __restrict__ cc) {
    __shared__ char smem[33280 + 32 * 132 * 4];      // 50176 B
    unsigned short* ldsX = (unsigned short*)smem;    // [32][520]
    unsigned short* ldsT = (unsigned short*)smem;    // [128][36] (reuse)
    float* hfull = (float*)(smem + 33280);           // [32][132]

    const int tid   = threadIdx.x;
    const int wv    = tid >> 6;
    const int lane  = tid & 63;
    const int m     = lane & 15;
    const int q     = lane >> 4;
    const int rowbase = blockIdx.x * 32;
    const int nbase   = (wv & 7) * 16;
    const int rhalf   = (wv >> 3) * 16;              // 0 or 16

    // ---- phase A: stage X tile (32 rows) -> LDS bf16
    {
        const int r  = tid >> 5;            // 0..31
        const int c0 = (tid & 31) * 16;     // 0..496
        const float* xp = X + (size_t)(rowbase + r) * TOKDIM + c0;
        bf16x8 v0, v1;
#pragma unroll
        for (int u = 0; u < 8; ++u) v0[u] = (short)f2bf(xp[u]);
#pragma unroll
        for (int u = 0; u < 8; ++u) v1[u] = (short)f2bf(xp[8 + u]);
        *(bf16x8*)&ldsX[r * 520 + c0]     = v0;
        *(bf16x8*)&ldsX[r * 520 + c0 + 8] = v1;
    }
    __syncthreads();

    // ---- phase B: MFMA. A[m][k] from ldsX (row-half offset), B from bf16 Wb.
    const unsigned short* wp = Wb + (size_t)(nbase + m) * TOKDIM + q * 8;
    f32x4 acc = {0.f, 0.f, 0.f, 0.f};
#pragma unroll
    for (int kk = 0; kk < TOKDIM / 32; ++kk) {
        bf16x8 a = *(const bf16x8*)&ldsX[(rhalf + m) * 520 + kk * 32 + q * 8];
        bf16x8 b = *(const bf16x8*)(wp + kk * 32);
        acc = __builtin_amdgcn_mfma_f32_16x16x32_bf16(a, b, acc, 0, 0, 0);
    }

    // ---- phase C: acc (+fc_b) -> hfull LDS  (validated C/D mapping)
    {
        const float bias = fcb[nbase + m];
#pragma unroll
        for (int r = 0; r < 4; ++r)
            hfull[(rhalf + q * 4 + r) * 132 + nbase + m] = acc[r] + bias;
    }
    __syncthreads();   // hfull ready; ldsX dead (safe to reuse as ldsT)

    // ---- phase D: LN + scores; write bf16 h into ldsT transposed
    {
        const int r   = tid >> 5;           // row 0..31
        const int l32 = tid & 31;
        const int c0  = l32 * 4;
        float4 hv = *(const float4*)&hfull[r * 132 + c0];
        float v[4] = {hv.x, hv.y, hv.z, hv.w};

        float s  = v[0] + v[1] + v[2] + v[3];
        float ss = v[0]*v[0] + v[1]*v[1] + v[2]*v[2] + v[3]*v[3];
#pragma unroll
        for (int d = 1; d < 32; d <<= 1) {
            s  += __shfl_xor(s,  d, 64);
            ss += __shfl_xor(ss, d, 64);
        }
        float mu  = s * (1.f / HID);
        float var = ss * (1.f / HID) - mu * mu;
        float rs  = rsqrtf(var + LN_EPS);

        float n[4], sr = 0.f, sc = 0.f;
#pragma unroll
        for (int k = 0; k < 4; ++k) {
            n[k] = lng[c0 + k] * (v[k] - mu) * rs + lnb[c0 + k];
            sr += n[k] * attnw[c0 + k];
            sc += n[k] * attnw[HID + c0 + k];
            ldsT[(c0 + k) * 36 + r] = f2bf(n[k]);
        }
#pragma unroll
        for (int d = 1; d < 32; d <<= 1) {
            sr += __shfl_xor(sr, d, 64);
            sc += __shfl_xor(sc, d, 64);
        }
        if (l32 == 0) {
            int grow = rowbase + r;
            srow[grow] = sr;
            cc[grow]   = sc + attnb[0];
        }
    }
    __syncthreads();

    // ---- phase E: coalesced hT write. thread t: d = t>>3, 4 j's of 32.
    {
        const int d  = tid >> 3;                   // 0..127
        const int j4 = (tid & 7) * 4;              // 0..28
        const int b    = blockIdx.x >> 6;          // 64 blocks per batch
        const int jblk = (blockIdx.x & 63) * 32;
        ushort4 o;
        o.x = ldsT[d * 36 + j4 + 0];
        o.y = ldsT[d * 36 + j4 + 1];
        o.z = ldsT[d * 36 + j4 + 2];
        o.w = ldsT[d * 36 + j4 + 3];
        *(ushort4*)(hT + ((size_t)(b * HID + d)) * NTOK + jblk + j4) = o;
    }
}

// ---------------------------------------------------------------------------
// k_attn v10 (wave-specialized): 256 blocks x 512 thr; block owns 32 i-rows;
// j in 8 chunks of 256.
// Producer waves 0-3 (256 thr): thread -> (i_loc = tid>>3, jsub = (tid&7)*32);
//   per chunk: 32 exp elements from prefetched srow regs -> 4 bf16x8 ds_writes
//   into pP[(ch+1)&1]. Owns lsum (-> pDen[32][8]).
// Consumer waves 4-7: wave cw=wv-4 -> d-group cw*32 (d-tiles +0,+16), full k.
//   Per s-step: 2 ds_reads feed 4 MFMAs (validated v11 acc semantics).
//   B-frags half-chunk double-buffered in static arrays bA/bB (no copies).
// Barriers ONLY at uniform program points; producer/consumer role-if inside.
// ---------------------------------------------------------------------------
__global__ __launch_bounds__(512) void k_attn(const unsigned short* __restrict__ hT,
                                              const float* __restrict__ srow,
                                              const float* __restrict__ cc,
                                              float* __restrict__ out) {
    __shared__ unsigned short pP[2][32][264];   // 2 x 16896 B, +8 pad
    __shared__ float pDen[32][8];               // 1 KB
    __shared__ float denv[32];

    const int tid  = threadIdx.x;
    const int wv   = tid >> 6;
    const int lane = tid & 63;
    const int m    = lane & 15;
    const int q    = lane >> 4;
    const int rowbase = blockIdx.x * 32;     // global row base
    const int b    = blockIdx.x >> 6;        // 64 blocks per batch
    const bool producer = (wv < 4);

    // ---- producer state
    const int i_loc = tid >> 3;              // 0..31 (valid for tid<256)
    const int jsub  = (tid & 7) * 32;        // 0..224
    float ci = 0.f;
    const float* sp = srow + (size_t)b * NTOK + jsub;
    float lsum = 0.f;
    float4 nxt[8];

    // ---- consumer state
    const int cw   = wv - 4;                 // 0..3
    const int dgrp = cw * 32;
    const unsigned short* hp0 =
        hT + ((size_t)(b * HID + dgrp + m)) * NTOK + q * 8;
    const unsigned short* hp1 = hp0 + 16 * NTOK;
    f32x4 acc00 = {0.f, 0.f, 0.f, 0.f};     // i 0-15,  d dgrp+m
    f32x4 acc01 = {0.f, 0.f, 0.f, 0.f};     // i 0-15,  d dgrp+16+m
    f32x4 acc10 = {0.f, 0.f, 0.f, 0.f};     // i 16-31, d dgrp+m
    f32x4 acc11 = {0.f, 0.f, 0.f, 0.f};     // i 16-31, d dgrp+16+m
    bf16x8 bA0[4], bA1[4], bB0[4], bB1[4];  // half-chunk double buffer

// produce 32 elements (4 x bf16x8) from float4 f[8] into pP[buf][i_loc][jsub..]
#define PRODUCE32(buf, F)                                                       \
    {                                                                           \
        unsigned short* dst = &pP[buf][i_loc][jsub];                            \
        _Pragma("unroll")                                                       \
        for (int g = 0; g < 4; ++g) {                                           \
            float e[8] = {F[2*g].x, F[2*g].y, F[2*g].z, F[2*g].w,               \
                          F[2*g+1].x, F[2*g+1].y, F[2*g+1].z, F[2*g+1].w};      \
            bf16x8 w;                                                           \
            _Pragma("unroll")                                                   \
            for (int u = 0; u < 8; ++u) {                                       \
                float z = ci + e[u];                                            \
                z = fmaxf(z, NEG_SLOPE * z);                                    \
                float p = __expf(z);                                            \
                lsum += p;                                                      \
                w[u] = (short)f2bf(p);                                          \
            }                                                                   \
            *(bf16x8*)(dst + g * 8) = w;                                        \
        }                                                                       \
    }

    // ---- prologue
    if (producer) {
        ci = cc[rowbase + i_loc];
        float4 cur[8];
#pragma unroll
        for (int g = 0; g < 8; ++g) cur[g] = *(const float4*)(sp + g * 4);
        PRODUCE32(0, cur)                          // chunk 0 -> pP[0]
#pragma unroll
        for (int g = 0; g < 8; ++g) nxt[g] = *(const float4*)(sp + 256 + g * 4);
    } else {
        // load first half of chunk 0 (s-steps 0..3)
#pragma unroll
        for (int s = 0; s < 4; ++s) {
            bA0[s] = *(const bf16x8*)(hp0 + s * 32);
            bA1[s] = *(const bf16x8*)(hp1 + s * 32);
        }
    }
    __syncthreads();   // pP[0] ready

#pragma unroll
    for (int ch = 0; ch < 8; ++ch) {
        if (producer) {
            if (ch < 7) {
                PRODUCE32((ch + 1) & 1, nxt)       // chunk ch+1
                if (ch < 6) {
                    const float* spn = sp + (ch + 2) * 256;
#pragma unroll
                    for (int g = 0; g < 8; ++g) nxt[g] = *(const float4*)(spn + g * 4);
                }
            } else {
                pDen[i_loc][tid & 7] = lsum;       // final chunk: publish sums
            }
        } else {
            // issue second half of chunk ch (s-steps 4..7)
#pragma unroll
            for (int s = 0; s < 4; ++s) {
                bB0[s] = *(const bf16x8*)(hp0 + ch * 256 + 128 + s * 32);
                bB1[s] = *(const bf16x8*)(hp1 + ch * 256 + 128 + s * 32);
            }
            // consume first half with bA
#pragma unroll
            for (int s = 0; s < 4; ++s) {
                bf16x8 a0 = *(const bf16x8*)&pP[ch & 1][m][s * 32 + q * 8];
                bf16x8 a1 = *(const bf16x8*)&pP[ch & 1][16 + m][s * 32 + q * 8];
                acc00 = __builtin_amdgcn_mfma_f32_16x16x32_bf16(a0, bA0[s], acc00, 0, 0, 0);
                acc01 = __builtin_amdgcn_mfma_f32_16x16x32_bf16(a0, bA1[s], acc01, 0, 0, 0);
                acc10 = __builtin_amdgcn_mfma_f32_16x16x32_bf16(a1, bA0[s], acc10, 0, 0, 0);
                acc11 = __builtin_amdgcn_mfma_f32_16x16x32_bf16(a1, bA1[s], acc11, 0, 0, 0);
            }
            // issue first half of chunk ch+1
            if (ch < 7) {
#pragma unroll
                for (int s = 0; s < 4; ++s) {
                    bA0[s] = *(const bf16x8*)(hp0 + (ch + 1) * 256 + s * 32);
                    bA1[s] = *(const bf16x8*)(hp1 + (ch + 1) * 256 + s * 32);
                }
            }
            // consume second half with bB
#pragma unroll
            for (int s = 0; s < 4; ++s) {
                bf16x8 a0 = *(const bf16x8*)&pP[ch & 1][m][128 + s * 32 + q * 8];
                bf16x8 a1 = *(const bf16x8*)&pP[ch & 1][16 + m][128 + s * 32 + q * 8];
                acc00 = __builtin_amdgcn_mfma_f32_16x16x32_bf16(a0, bB0[s], acc00, 0, 0, 0);
                acc01 = __builtin_amdgcn_mfma_f32_16x16x32_bf16(a0, bB1[s], acc01, 0, 0, 0);
                acc10 = __builtin_amdgcn_mfma_f32_16x16x32_bf16(a1, bB0[s], acc10, 0, 0, 0);
                acc11 = __builtin_amdgcn_mfma_f32_16x16x32_bf16(a1, bB1[s], acc11, 0, 0, 0);
            }
        }
        __syncthreads();   // pP[(ch+1)&1] published; chunk ch fully consumed
    }
#undef PRODUCE32

    // ---- denominators
    if (tid < 32) {
        float d = 0.f;
#pragma unroll
        for (int k = 0; k < 8; ++k) d += pDen[tid][k];
        denv[tid] = 1.f / d;
    }
    __syncthreads();

    // ---- epilogue: consumers write out (validated C/D mapping)
    if (!producer) {
#pragma unroll
        for (int r = 0; r < 4; ++r) {
            int r0 = q * 4 + r;
            out[(size_t)(rowbase + r0) * HID + dgrp + m]           = acc00[r] * denv[r0];
            out[(size_t)(rowbase + r0) * HID + dgrp + 16 + m]      = acc01[r] * denv[r0];
            out[(size_t)(rowbase + 16 + r0) * HID + dgrp + m]      = acc10[r] * denv[16 + r0];
            out[(size_t)(rowbase + 16 + r0) * HID + dgrp + 16 + m] = acc11[r] * denv[16 + r0];
        }
    }
}

// ---------------------------------------------------------------------------
extern "C" void kernel_launch(void* const* d_in, const int* in_sizes, int n_in,
                              void* d_out, int out_size, void* d_ws, size_t ws_size,
                              hipStream_t stream) {
    const float* X     = (const float*)d_in[0]; // token_embedding [4,2048,512]
    const float* W     = (const float*)d_in[1]; // fc_w [128,512]
    const float* fcb   = (const float*)d_in[2]; // fc_b [128]
    const float* attnw = (const float*)d_in[3]; // attn_w [1,256]
    const float* attnb = (const float*)d_in[4]; // attn_b [1]
    const float* lng   = (const float*)d_in[5]; // ln_g [128]
    const float* lnb   = (const float*)d_in[6]; // ln_b [128]
    float* out = (float*)d_out;                 // h_prime [4,2048,128] fp32

    char* ws = (char*)d_ws;
    unsigned short* hT   = (unsigned short*)ws;                          // 2 MB
    float*          srow = (float*)(ws + 2u * 1024 * 1024);              // 32 KB
    float*          cchd = (float*)(ws + 2u * 1024 * 1024 + 32u * 1024); // 32 KB
    unsigned short* Wb   = (unsigned short*)(ws + 2u * 1024 * 1024 + 64u * 1024); // 128 KB

    k_prep <<<64, 256, 0, stream>>>(W, Wb);
    k_fused<<<NROWS / 32, 1024, 0, stream>>>(X, Wb, fcb, attnw, attnb, lng, lnb,
                                             hT, srow, cchd);
    k_attn <<<NROWS / 32, 512, 0, stream>>>(hT, srow, cchd, out);
}